// Round 1
// baseline (91.802 us; speedup 1.0000x reference)
//
#include <hip/hip_runtime.h>

// Diagonal depthwise conv, derived from the reference:
//   View x as X[R][W], R = B*C*H = 131072, W = 256.
//   out[r][w] = bias[c] + sum_k weight[c][k] * X[(r+2-k) mod R][w+k-2]
//   where c = (r / H) % C, column OOB -> 0, row index wraps mod R
//   (torch.roll on the fully-flattened tensor wraps across h/c/b).

#define WIDTH 256
#define RTOT  131072   // 8 * 64 * 256
#define NCH   64
#define KS    5

__global__ __launch_bounds__(256) void diag_dwconv_kernel(
    const float* __restrict__ x,
    const float* __restrict__ wgt,    // [C][1][KS] flat
    const float* __restrict__ bias,   // [C]
    float* __restrict__ out,
    int nvec)                         // total float4 outputs
{
    int idx    = blockIdx.x * blockDim.x + threadIdx.x;
    int stride = gridDim.x * blockDim.x;

    for (int v = idx; v < nvec; v += stride) {
        int r  = v >> 6;            // W/4 = 64 float4 per row
        int w0 = (v & 63) << 2;     // first output column
        int c  = (r >> 8) & (NCH - 1);

        const float* wc = wgt + c * KS;
        float b = bias[c];
        float acc0 = b, acc1 = b, acc2 = b, acc3 = b;

        #pragma unroll
        for (int k = 0; k < KS; ++k) {
            int rk = r + 2 - k;                 // source row (anti-diagonal)
            if (rk < 0)          rk += RTOT;    // wrap across flat tensor
            else if (rk >= RTOT) rk -= RTOT;
            const float* xr = x + (size_t)rk * WIDTH;
            float wk = wc[k];
            int cbase = w0 + k - 2;             // first source column

            if (cbase >= 0 && cbase + 3 < WIDTH) {
                // interior fast path (all but lanes at w0==0 / w0==252)
                acc0 = fmaf(wk, xr[cbase + 0], acc0);
                acc1 = fmaf(wk, xr[cbase + 1], acc1);
                acc2 = fmaf(wk, xr[cbase + 2], acc2);
                acc3 = fmaf(wk, xr[cbase + 3], acc3);
            } else {
                int cc;
                cc = cbase + 0; if (cc >= 0 && cc < WIDTH) acc0 = fmaf(wk, xr[cc], acc0);
                cc = cbase + 1; if (cc >= 0 && cc < WIDTH) acc1 = fmaf(wk, xr[cc], acc1);
                cc = cbase + 2; if (cc >= 0 && cc < WIDTH) acc2 = fmaf(wk, xr[cc], acc2);
                cc = cbase + 3; if (cc >= 0 && cc < WIDTH) acc3 = fmaf(wk, xr[cc], acc3);
            }
        }

        float4 o = make_float4(acc0, acc1, acc2, acc3);
        reinterpret_cast<float4*>(out)[v] = o;
    }
}

extern "C" void kernel_launch(void* const* d_in, const int* in_sizes, int n_in,
                              void* d_out, int out_size, void* d_ws, size_t ws_size,
                              hipStream_t stream) {
    const float* x    = (const float*)d_in[0];
    const float* wgt  = (const float*)d_in[1];
    const float* bias = (const float*)d_in[2];
    float* out        = (float*)d_out;

    int nvec = out_size / 4;        // 8,388,608 / 4-wide
    int threads = 256;
    int blocks  = 2048;             // grid-stride, ~8 blocks/CU
    diag_dwconv_kernel<<<blocks, threads, 0, stream>>>(x, wgt, bias, out, nvec);
}

// Round 2
// 56.121 us; speedup vs baseline: 1.6358x; 1.6358x over previous
//
#include <hip/hip_runtime.h>

// Diagonal depthwise conv, derived from the reference:
//   View x as X[R][W], R = B*C*H = 131072, W = 256.
//   out[r][w] = bias[c] + sum_k weight[c][k] * X[(r+2-k) mod R][w+k-2]
//   where c = (r / H) % C, column OOB -> 0, row index wraps mod R
//   (torch.roll on the fully-flattened tensor wraps across h/c/b).
//
// Each thread computes 8 contiguous outputs of one row. Per source row k
// (each row feeds exactly one tap), load the 12-float window covering
// cols w0-2 .. w0+9 as float2+float4+float4+float2 (all naturally aligned),
// zero the 2 boundary floats when w0 is at the row edge (no divergent
// per-tap branches), and accumulate acc[j] += w[k] * F[j+k].

#define WIDTH 256
#define RTOT  131072            // 8 * 64 * 256
#define NTOT  (RTOT * WIDTH)    // 33,554,432 (fits int)
#define NCH   64
#define KS    5

__global__ __launch_bounds__(256) void diag_dwconv_kernel(
    const float* __restrict__ x,
    const float* __restrict__ wgt,    // [C][1][KS] flat
    const float* __restrict__ bias,   // [C]
    float* __restrict__ out)
{
    int v  = blockIdx.x * blockDim.x + threadIdx.x;  // [0, RTOT*32)
    int r  = v >> 5;                 // 32 8-wide segments per row
    int w0 = (v & 31) << 3;          // first output column
    int c  = (r >> 8) & (NCH - 1);

    float b = bias[c];
    float acc[8];
    #pragma unroll
    for (int j = 0; j < 8; ++j) acc[j] = b;

    #pragma unroll
    for (int k = 0; k < KS; ++k) {
        int rk = r + 2 - k;                       // source row (anti-diagonal)
        if (rk < 0)          rk += RTOT;          // wrap across flat tensor
        else if (rk >= RTOT) rk -= RTOT;
        int base = rk * WIDTH + w0;

        int loff = base - 2;                      // OOB only if rk==0 && w0==0
        if (loff < 0) loff = 0;                   // loaded value is masked
        int roff = base + 8;                      // OOB only if rk==RTOT-1 && w0==248
        if (roff > NTOT - 2) roff = NTOT - 2;     // loaded value is masked

        float2 L  = *reinterpret_cast<const float2*>(x + loff);   // cols w0-2, w0-1
        float4 M1 = *reinterpret_cast<const float4*>(x + base);   // cols w0 .. w0+3
        float4 M2 = *reinterpret_cast<const float4*>(x + base + 4); // w0+4 .. w0+7
        float2 R  = *reinterpret_cast<const float2*>(x + roff);   // cols w0+8, w0+9

        // column boundary: zero contributions outside [0, WIDTH)
        if (w0 == 0)         { L.x = 0.f; L.y = 0.f; }
        if (w0 == WIDTH - 8) { R.x = 0.f; R.y = 0.f; }

        float F[12] = { L.x, L.y,
                        M1.x, M1.y, M1.z, M1.w,
                        M2.x, M2.y, M2.z, M2.w,
                        R.x, R.y };

        float wk = wgt[c * KS + k];
        #pragma unroll
        for (int j = 0; j < 8; ++j)
            acc[j] = fmaf(wk, F[j + k], acc[j]);  // col = w0 + j + (k-2)
    }

    int ob = r * WIDTH + w0;
    *reinterpret_cast<float4*>(out + ob)     = make_float4(acc[0], acc[1], acc[2], acc[3]);
    *reinterpret_cast<float4*>(out + ob + 4) = make_float4(acc[4], acc[5], acc[6], acc[7]);
}

extern "C" void kernel_launch(void* const* d_in, const int* in_sizes, int n_in,
                              void* d_out, int out_size, void* d_ws, size_t ws_size,
                              hipStream_t stream) {
    const float* x    = (const float*)d_in[0];
    const float* wgt  = (const float*)d_in[1];
    const float* bias = (const float*)d_in[2];
    float* out        = (float*)d_out;

    // one thread per 8 outputs: 8,388,608 / 8 = 1,048,576 threads... wait
    // out_size = 8*64*256*256 = 4,194,304? No: 8*64*256*256 = 33,554,432.
    // threads = NTOT/8 = 4,194,304 -> 16384 blocks of 256.
    int threads = 256;
    int blocks  = (out_size / 8 + threads - 1) / threads;
    diag_dwconv_kernel<<<blocks, threads, 0, stream>>>(x, wgt, bias, out);
}